// Round 20
// baseline (350.672 us; speedup 1.0000x reference)
//
#include <hip/hip_runtime.h>
#include <hip/hip_bf16.h>
#include <math.h>

#define N_NODES 50000
#define N_EDGES 1600000
#define NODE_IN 128
#define HID 64
#define NODEF (N_NODES * HID)   // 3,200,000 elements per node buffer
#define EBLK 64                 // edges per block in edge_fused (E % EBLK == 0)
#define MM1_BLOCKS 1563         // ceil(50000/32)
#define DEG_BLOCKS 6250         // 1.6M / 256
#define NWIN 8                  // dst windows for fill_csr (50000/8 = 6250)
#define SCAN_BLOCKS 49          // ceil(50000/1024)
#define FILL_BLOCKS (NWIN * DEG_BLOCKS)   // 50000, dispatched FIRST

typedef __hip_bfloat16 bf16;
typedef _Float16 half2t __attribute__((ext_vector_type(2)));
typedef _Float16 half4t __attribute__((ext_vector_type(4)));
typedef float f32x4 __attribute__((ext_vector_type(4)));

__device__ __forceinline__ float bf2f(bf16 v) { return __bfloat162float(v); }
__device__ __forceinline__ bf16 f2bf(float v) { return __float2bfloat16(v); }

// ---------------- degree count (standalone; feeds scan)
__global__ __launch_bounds__(256) void deg_count_i(const int* __restrict__ dst,
                                                   int* __restrict__ degi, int E) {
    int e = blockIdx.x * blockDim.x + threadIdx.x;
    if (e < E) atomicAdd(&degi[dst[e]], 1);
}

// ---------------- hierarchical scan, stage 1: per-block sums
__global__ __launch_bounds__(1024) void scan_blocks(const int* __restrict__ degi,
                                                    int* __restrict__ partial) {
    __shared__ int wsum[16];
    const int t = threadIdx.x;
    const int i = blockIdx.x * 1024 + t;
    const int lane = t & 63, w = t >> 6;
    int v = (i < N_NODES) ? degi[i] : 0;
#pragma unroll
    for (int d = 32; d; d >>= 1) v += __shfl_xor(v, d, 64);
    if (lane == 0) wsum[w] = v;
    __syncthreads();
    if (t == 0) {
        int s = 0;
#pragma unroll
        for (int k = 0; k < 16; ++k) s += wsum[k];
        partial[blockIdx.x] = s;
    }
}

// ---------------- stage 2: exclusive scan of 49 partials (one wave)
__global__ __launch_bounds__(64) void scan_tops(const int* __restrict__ partial,
                                                int* __restrict__ base) {
    const int t = threadIdx.x;
    int v = (t < SCAN_BLOCKS) ? partial[t] : 0;
    int inc = v;
#pragma unroll
    for (int d = 1; d < 64; d <<= 1) {
        int u = __shfl_up(inc, d, 64);
        if (t >= d) inc += u;
    }
    if (t < SCAN_BLOCKS) base[t] = inc - v;
}

// ---------------- stage 3: per-block exclusive scan + base, coalesced writes
__global__ __launch_bounds__(1024) void scan_final(const int* __restrict__ degi,
                                                   const int* __restrict__ base,
                                                   int* __restrict__ off,
                                                   int* __restrict__ cursor) {
    __shared__ int wsum[16];
    const int t = threadIdx.x;
    const int i = blockIdx.x * 1024 + t;
    const int lane = t & 63, w = t >> 6;
    int v = (i < N_NODES) ? degi[i] : 0;
    int inc = v;
#pragma unroll
    for (int d = 1; d < 64; d <<= 1) {
        int u = __shfl_up(inc, d, 64);
        if (lane >= d) inc += u;
    }
    if (lane == 63) wsum[w] = inc;
    __syncthreads();
    if (w == 0) {
        int s = (lane < 16) ? wsum[lane] : 0;
#pragma unroll
        for (int d = 1; d < 16; d <<= 1) {
            int u = __shfl_up(s, d, 64);
            if (lane >= d) s += u;
        }
        if (lane < 16) wsum[lane] = s;   // inclusive wave sums
    }
    __syncthreads();
    const int wbase = (w > 0) ? wsum[w - 1] : 0;
    const int excl = base[blockIdx.x] + wbase + inc - v;
    if (i < N_NODES) { off[i] = excl; cursor[i] = excl; }
    if (i == N_NODES) off[i] = excl;     // total edge count
}

// ---------------- combined windowed CSR fill + conv1 GEMM, FILL-FIRST:
// fill blocks [0,50000) run compact (temporally dense windows -> csr stores
// stay L2-resident, ~1x write amplification); GEMM blocks trail and overlap
// the fill's drain.
__global__ __launch_bounds__(256) void conv1_fill(const float* __restrict__ in,
                                                  const float* __restrict__ Wa,
                                                  const float* __restrict__ Wb,
                                                  bf16* __restrict__ out1,
                                                  float* __restrict__ out2,
                                                  const int* __restrict__ src,
                                                  const int* __restrict__ dst,
                                                  int* __restrict__ cursor,
                                                  int* __restrict__ csr, int N) {
    constexpr int K = 128, ROWS = 32, PAD = 36;
    __shared__ float xs[K * PAD];
    const int bid = blockIdx.x;
    if (bid < FILL_BLOCKS) {
        // windowed fill_csr: pass-major over NWIN windows
        int w = bid / DEG_BLOCKS;
        int chunk = bid % DEG_BLOCKS;
        int e = chunk * 256 + threadIdx.x;
        int d = dst[e];
        int lo = w * (N_NODES / NWIN);
        int hi = lo + (N_NODES / NWIN);
        if (d >= lo && d < hi) {
            int p = atomicAdd(&cursor[d], 1);
            csr[p] = src[e];
        }
        return;
    }
    const int row0 = (bid - FILL_BLOCKS) * ROWS;
    const int ty = threadIdx.x >> 6;
    const int col = threadIdx.x & 63;
    for (int i = threadIdx.x; i < ROWS * K; i += 256) {
        int r = i / K, c = i % K;
        int row = row0 + r;
        xs[c * PAD + r] = (row < N) ? in[(size_t)row * K + c] : 0.f;
    }
    __syncthreads();
    float a1[8], a2[8];
#pragma unroll
    for (int m = 0; m < 8; ++m) { a1[m] = 0.f; a2[m] = 0.f; }
#pragma unroll 4
    for (int k = 0; k < K; ++k) {
        const float4* xr = (const float4*)(xs + k * PAD + ty * 8);
        float4 xa = xr[0], xb = xr[1];
        float wa = Wa[k * 64 + col];
        float wb = Wb[k * 64 + col];
        a1[0] = fmaf(xa.x, wa, a1[0]); a2[0] = fmaf(xa.x, wb, a2[0]);
        a1[1] = fmaf(xa.y, wa, a1[1]); a2[1] = fmaf(xa.y, wb, a2[1]);
        a1[2] = fmaf(xa.z, wa, a1[2]); a2[2] = fmaf(xa.z, wb, a2[2]);
        a1[3] = fmaf(xa.w, wa, a1[3]); a2[3] = fmaf(xa.w, wb, a2[3]);
        a1[4] = fmaf(xb.x, wa, a1[4]); a2[4] = fmaf(xb.x, wb, a2[4]);
        a1[5] = fmaf(xb.y, wa, a1[5]); a2[5] = fmaf(xb.y, wb, a2[5]);
        a1[6] = fmaf(xb.z, wa, a1[6]); a2[6] = fmaf(xb.z, wb, a2[6]);
        a1[7] = fmaf(xb.w, wa, a1[7]); a2[7] = fmaf(xb.w, wb, a2[7]);
    }
#pragma unroll
    for (int m = 0; m < 8; ++m) {
        int row = row0 + ty * 8 + m;
        if (row < N) {
            unsigned idx = ((unsigned)row << 6) + col;
            out1[idx] = f2bf(a1[m]);
            out2[idx] = a2[m];
        }
    }
}

// ---------------- fused gather + dual GEMM (R13/R18 form: 16-node tile,
// LDS-staged indices, f32 FMA GEMM phase):
//   h = ReLU(mean_{s in N(d)} y[s] + bias + r) -> LDS(T) -> out1/out2 = h@W
template <bool OUT1_BF, bool OUT2_BF>
__global__ __launch_bounds__(256) void gather_mm(const bf16* __restrict__ y,
                                                 const float* __restrict__ r,
                                                 const int* __restrict__ csr,
                                                 const int* __restrict__ off,
                                                 const float* __restrict__ bias,
                                                 const float* __restrict__ Wa,
                                                 const float* __restrict__ Wb,
                                                 void* __restrict__ out1v,
                                                 void* __restrict__ out2v, int N) {
    constexpr int K = 64, ROWS = 16, PAD = 20, IDXCAP = 256;
    __shared__ float xs[K * PAD];           // 5 KB
    __shared__ int   idx_s[4][IDXCAP];      // 4 KB (1 KB per wave)
    const int row0 = blockIdx.x * ROWS;     // N % 16 == 0 -> all nodes valid
    const int j  = threadIdx.x & 63;
    const int wv = threadIdx.x >> 6;
    const float bj = bias[j];

    const int nbase = row0 + wv * 4;
    int offs[5];
#pragma unroll
    for (int i = 0; i < 5; ++i) offs[i] = off[nbase + i];
    const int segS = offs[0];
    const int len = offs[4] - segS;
    int* idx_w = idx_s[wv];
    const bool useLds = (len <= IDXCAP);
    if (useLds) {
        for (int i = j; i < len; i += 64)
            idx_w[i] = csr[segS + i];        // coalesced; wave-private slab
    }

    // ---- gather phase: wave wv produces rows wv*4 .. wv*4+3
    for (int m = 0; m < 4; ++m) {
        int lr = wv * 4 + m;
        int node = row0 + lr;
        float acc = 0.f;
        int deg = offs[m + 1] - offs[m];
        if (useLds) {
            int k = offs[m] - segS, s1 = offs[m + 1] - segS;
            for (; k + 15 < s1; k += 16) {
                int sidx[16];
#pragma unroll
                for (int u = 0; u < 16; ++u) sidx[u] = idx_w[k + u];
                float v[16];
#pragma unroll
                for (int u = 0; u < 16; ++u) v[u] = bf2f(y[((unsigned)sidx[u] << 6) + j]);
                float s = 0.f;
#pragma unroll
                for (int u = 0; u < 16; ++u) s += v[u];
                acc += s;
            }
            for (; k + 3 < s1; k += 4) {
                int sa = idx_w[k], sb = idx_w[k + 1], sc = idx_w[k + 2], sd = idx_w[k + 3];
                float va = bf2f(y[((unsigned)sa << 6) + j]);
                float vb = bf2f(y[((unsigned)sb << 6) + j]);
                float vc = bf2f(y[((unsigned)sc << 6) + j]);
                float vd = bf2f(y[((unsigned)sd << 6) + j]);
                acc += (va + vb) + (vc + vd);
            }
            for (; k < s1; ++k)
                acc += bf2f(y[((unsigned)idx_w[k] << 6) + j]);
        } else {
            int k = offs[m], s1 = offs[m + 1];
            for (; k + 15 < s1; k += 16) {
                int sidx[16];
#pragma unroll
                for (int u = 0; u < 16; ++u) sidx[u] = csr[k + u];
                float v[16];
#pragma unroll
                for (int u = 0; u < 16; ++u) v[u] = bf2f(y[((unsigned)sidx[u] << 6) + j]);
                float s = 0.f;
#pragma unroll
                for (int u = 0; u < 16; ++u) s += v[u];
                acc += s;
            }
            for (; k + 3 < s1; k += 4) {
                int sa = csr[k], sb = csr[k + 1], sc = csr[k + 2], sd = csr[k + 3];
                float va = bf2f(y[((unsigned)sa << 6) + j]);
                float vb = bf2f(y[((unsigned)sb << 6) + j]);
                float vc = bf2f(y[((unsigned)sc << 6) + j]);
                float vd = bf2f(y[((unsigned)sd << 6) + j]);
                acc += (va + vb) + (vc + vd);
            }
            for (; k < s1; ++k)
                acc += bf2f(y[((unsigned)csr[k] << 6) + j]);
        }
        float mean = acc / fmaxf((float)deg, 1.f);
        float val = fmaxf(mean + bj + r[((unsigned)node << 6) + j], 0.f);
        xs[j * PAD + lr] = val;     // transposed for GEMM
    }
    __syncthreads();

    // ---- GEMM phase: each wave computes 4 output rows x 64 cols
    float a1[4], a2[4];
#pragma unroll
    for (int m = 0; m < 4; ++m) { a1[m] = 0.f; a2[m] = 0.f; }
#pragma unroll 4
    for (int k = 0; k < K; ++k) {
        const float4 xa = *(const float4*)(xs + k * PAD + wv * 4);  // broadcast
        float wa = Wa[k * 64 + j];
        float wb = Wb[k * 64 + j];
        a1[0] = fmaf(xa.x, wa, a1[0]); a2[0] = fmaf(xa.x, wb, a2[0]);
        a1[1] = fmaf(xa.y, wa, a1[1]); a2[1] = fmaf(xa.y, wb, a2[1]);
        a1[2] = fmaf(xa.z, wa, a1[2]); a2[2] = fmaf(xa.z, wb, a2[2]);
        a1[3] = fmaf(xa.w, wa, a1[3]); a2[3] = fmaf(xa.w, wb, a2[3]);
    }
#pragma unroll
    for (int m = 0; m < 4; ++m) {
        int row = row0 + wv * 4 + m;
        if (row < N) {
            unsigned idx = ((unsigned)row << 6) + j;
            if (OUT1_BF) ((bf16*)out1v)[idx] = f2bf(a1[m]);
            else         ((float*)out1v)[idx] = a1[m];
            if (OUT2_BF) ((bf16*)out2v)[idx] = f2bf(a2[m]);
            else         ((float*)out2v)[idx] = a2[m];
        }
    }
}

// ---------------- fused edge stage, MFMA form (R18, refcheck-validated)
__global__ __launch_bounds__(256) void edge_fused(const bf16* __restrict__ aE,
                                                  const bf16* __restrict__ bE,
                                                  const float* __restrict__ ea,
                                                  const float* __restrict__ Wbot,
                                                  const float* __restrict__ bm1,
                                                  const float* __restrict__ wm2,
                                                  const float* __restrict__ bm2,
                                                  const int* __restrict__ src,
                                                  const int* __restrict__ dst,
                                                  float* __restrict__ out) {
    __shared__ __align__(16) unsigned ea_s[EBLK * 8];  // rows of 16 f16 (2 KB)
    const int t   = threadIdx.x;
    const int eb0 = blockIdx.x * EBLK;
    const int j   = t & 63;
    const int wv  = t >> 6;
    const int lo  = j & 15;     // D col within 16-group / A row
    const int hi  = j >> 4;     // k-block / D row-group

    {   // stage ea -> f16 pairs (coalesced float2 reads)
        const float2* eaf2 = (const float2*)(ea + (size_t)eb0 * 16);
        for (int i = t; i < EBLK * 8; i += 256) {
            float2 f = eaf2[i];
            half2t p;
            p.x = (_Float16)f.x;
            p.y = (_Float16)f.y;
            ea_s[i] = __builtin_bit_cast(unsigned, p);
        }
    }

    // B operand: wb[m][i] = f16(Wbot[k = hi*4+i][col = 16m+lo])
    half4t wb[4];
#pragma unroll
    for (int m = 0; m < 4; ++m)
#pragma unroll
        for (int i = 0; i < 4; ++i)
            wb[m][i] = (_Float16)Wbot[(hi * 4 + i) * 64 + 16 * m + lo];
    float bm1c[4], wm2c[4];
#pragma unroll
    for (int m = 0; m < 4; ++m) {
        bm1c[m] = bm1[16 * m + lo];
        wm2c[m] = wm2[16 * m + lo];
    }
    const float bm2c = bm2[0];

    // wave's 16 edges: lane p holds edge (p&15)'s src/dst
    const int ebw = eb0 + wv * 16;
    const int vsrc = src[ebw + lo];
    const int vdst = dst[ebw + lo];
    __syncthreads();

    // A operand: ea[edge = wv*16 + lo][k = hi*4 .. hi*4+3]  (one ds_read_b64)
    const uint2 a2v = *(const uint2*)(ea_s + (wv * 16 + lo) * 8 + hi * 2);
    const half4t a = __builtin_bit_cast(half4t, a2v);

    f32x4 acc[4];
#pragma unroll
    for (int m = 0; m < 4; ++m)
        acc[m] = (f32x4){bm1c[m], bm1c[m], bm1c[m], bm1c[m]};
#pragma unroll
    for (int m = 0; m < 4; ++m)
        acc[m] = __builtin_amdgcn_mfma_f32_16x16x16f16(a, wb[m], acc[m], 0, 0, 0);

    // per lane: 4 edge rows (hi*4+r), 4 cols (16m+lo)
    const ushort* aU = (const ushort*)aE;
    const ushort* bU = (const ushort*)bE;
    float esum[4];
#pragma unroll
    for (int r = 0; r < 4; ++r) {
        int s = __shfl(vsrc, hi * 4 + r, 16);   // edge (hi*4+r)'s src
        int d = __shfl(vdst, hi * 4 + r, 16);
        const ushort* ap = aU + ((unsigned)s << 6) + lo;
        const ushort* bp = bU + ((unsigned)d << 6) + lo;
        ushort au[4], bu[4];
#pragma unroll
        for (int m = 0; m < 4; ++m) { au[m] = ap[16 * m]; bu[m] = bp[16 * m]; }
        float sum = 0.f;
#pragma unroll
        for (int m = 0; m < 4; ++m) {
            float v = acc[m][r] + bf2f(*(const bf16*)&au[m]) + bf2f(*(const bf16*)&bu[m]);
            sum = fmaf(fmaxf(v, 0.f), wm2c[m], sum);
        }
        esum[r] = sum;
    }
    // reduce over the 16 lanes of each group
#pragma unroll
    for (int o = 1; o < 16; o <<= 1) {
#pragma unroll
        for (int r = 0; r < 4; ++r) esum[r] += __shfl_xor(esum[r], o, 16);
    }
    if (lo == 0) {
#pragma unroll
        for (int r = 0; r < 4; ++r)
            out[ebw + hi * 4 + r] = 1.f / (1.f + __expf(-(esum[r] + bm2c)));
    }
}

extern "C" void kernel_launch(void* const* d_in, const int* in_sizes, int n_in,
                              void* d_out, int out_size, void* d_ws, size_t ws_size,
                              hipStream_t stream) {
    const float* x         = (const float*)d_in[0];
    const float* edge_attr = (const float*)d_in[1];
    const float* W1l       = (const float*)d_in[2];
    const float* b1l       = (const float*)d_in[3];
    const float* W1r       = (const float*)d_in[4];
    const float* W2l       = (const float*)d_in[5];
    const float* b2l       = (const float*)d_in[6];
    const float* W2r       = (const float*)d_in[7];
    const float* Wm1       = (const float*)d_in[8];
    const float* bm1       = (const float*)d_in[9];
    const float* Wm2       = (const float*)d_in[10];
    const float* bm2       = (const float*)d_in[11];
    const int*   ei        = (const int*)d_in[12];   // [2, E] int32
    const int*   src       = ei;
    const int*   dst       = ei + N_EDGES;
    float* out = (float*)d_out;

    int*   degi    = (int*)d_ws;
    int*   off     = degi + 50176;
    int*   cursor  = off + 50432;
    int*   partial = cursor + 50000;
    int*   base    = cursor + 50064;
    int*   csr     = cursor + 50176;
    bf16*  bfA     = (bf16*)(csr + N_EDGES);  // y1 / aE
    bf16*  bfB     = bfA + NODEF;             // y2
    bf16*  bfC     = bfB + NODEF;             // bE
    float* fR      = (float*)(bfC + NODEF);   // r1
    float* fR2     = fR + NODEF;              // r2

    const int N = N_NODES, E = N_EDGES;
    const int gmGrid = (N + 15) / 16;        // 3125
    const int efGrid = E / EBLK;

    // ---- CSR degree + offsets (small, parallel)
    hipMemsetAsync(degi, 0, N_NODES * sizeof(int), stream);
    deg_count_i<<<DEG_BLOCKS, 256, 0, stream>>>(dst, degi, E);
    scan_blocks<<<SCAN_BLOCKS, 1024, 0, stream>>>(degi, partial);
    scan_tops<<<1, 64, 0, stream>>>(partial, base);
    scan_final<<<SCAN_BLOCKS, 1024, 0, stream>>>(degi, base, off, cursor);

    // ---- windowed CSR fill (first, compact) + conv1 GEMM (trailing)
    conv1_fill<<<FILL_BLOCKS + MM1_BLOCKS, 256, 0, stream>>>(
        x, W1l, W1r, bfA, fR, src, dst, cursor, csr, N);

    // ---- conv2: gather h1 (from y1,r1) fused with y2 = h1@W2l, r2 = h1@W2r
    gather_mm<true, false><<<gmGrid, 256, 0, stream>>>(
        bfA, fR, csr, off, b1l, W2l, W2r, bfB, fR2, N);

    // ---- edge precompute: gather h2 (from y2,r2) fused with aE/bE = h2@Wm1 halves
    gather_mm<true, true><<<gmGrid, 256, 0, stream>>>(
        bfB, fR2, csr, off, b2l, Wm1, Wm1 + 64 * 64, bfA, bfC, N);

    // ---- fused edge MLP (MFMA)
    edge_fused<<<efGrid, 256, 0, stream>>>(bfA, bfC, edge_attr, Wm1 + 128 * 64,
                                           bm1, Wm2, bm2, src, dst, out);
}

// Round 21
// 325.169 us; speedup vs baseline: 1.0784x; 1.0784x over previous
//
#include <hip/hip_runtime.h>
#include <hip/hip_bf16.h>
#include <math.h>

#define N_NODES 50000
#define N_EDGES 1600000
#define NODE_IN 128
#define HID 64
#define NODEF (N_NODES * HID)   // 3,200,000 elements per node buffer
#define EBLK 64                 // edges per block in edge_fused (E % EBLK == 0)
#define MM1_BLOCKS 1563         // ceil(50000/32)
#define DEG_BLOCKS 6250         // 1.6M / 256
#define NWIN 4                  // dst windows for fill_csr (50000/4 = 12500)
#define SCAN_BLOCKS 49          // ceil(50000/1024)

typedef __hip_bfloat16 bf16;
typedef _Float16 half2t __attribute__((ext_vector_type(2)));
typedef _Float16 half4t __attribute__((ext_vector_type(4)));
typedef float f32x4 __attribute__((ext_vector_type(4)));

__device__ __forceinline__ float bf2f(bf16 v) { return __bfloat162float(v); }
__device__ __forceinline__ bf16 f2bf(float v) { return __float2bfloat16(v); }

// ---------------- degree count (standalone; feeds scan)
__global__ __launch_bounds__(256) void deg_count_i(const int* __restrict__ dst,
                                                   int* __restrict__ degi, int E) {
    int e = blockIdx.x * blockDim.x + threadIdx.x;
    if (e < E) atomicAdd(&degi[dst[e]], 1);
}

// ---------------- hierarchical scan, stage 1: per-block sums
__global__ __launch_bounds__(1024) void scan_blocks(const int* __restrict__ degi,
                                                    int* __restrict__ partial) {
    __shared__ int wsum[16];
    const int t = threadIdx.x;
    const int i = blockIdx.x * 1024 + t;
    const int lane = t & 63, w = t >> 6;
    int v = (i < N_NODES) ? degi[i] : 0;
#pragma unroll
    for (int d = 32; d; d >>= 1) v += __shfl_xor(v, d, 64);
    if (lane == 0) wsum[w] = v;
    __syncthreads();
    if (t == 0) {
        int s = 0;
#pragma unroll
        for (int k = 0; k < 16; ++k) s += wsum[k];
        partial[blockIdx.x] = s;
    }
}

// ---------------- stage 2: exclusive scan of 49 partials (one wave)
__global__ __launch_bounds__(64) void scan_tops(const int* __restrict__ partial,
                                                int* __restrict__ base) {
    const int t = threadIdx.x;
    int v = (t < SCAN_BLOCKS) ? partial[t] : 0;
    int inc = v;
#pragma unroll
    for (int d = 1; d < 64; d <<= 1) {
        int u = __shfl_up(inc, d, 64);
        if (t >= d) inc += u;
    }
    if (t < SCAN_BLOCKS) base[t] = inc - v;
}

// ---------------- stage 3: per-block exclusive scan + base, coalesced writes
__global__ __launch_bounds__(1024) void scan_final(const int* __restrict__ degi,
                                                   const int* __restrict__ base,
                                                   int* __restrict__ off,
                                                   int* __restrict__ cursor) {
    __shared__ int wsum[16];
    const int t = threadIdx.x;
    const int i = blockIdx.x * 1024 + t;
    const int lane = t & 63, w = t >> 6;
    int v = (i < N_NODES) ? degi[i] : 0;
    int inc = v;
#pragma unroll
    for (int d = 1; d < 64; d <<= 1) {
        int u = __shfl_up(inc, d, 64);
        if (lane >= d) inc += u;
    }
    if (lane == 63) wsum[w] = inc;
    __syncthreads();
    if (w == 0) {
        int s = (lane < 16) ? wsum[lane] : 0;
#pragma unroll
        for (int d = 1; d < 16; d <<= 1) {
            int u = __shfl_up(s, d, 64);
            if (lane >= d) s += u;
        }
        if (lane < 16) wsum[lane] = s;   // inclusive wave sums
    }
    __syncthreads();
    const int wbase = (w > 0) ? wsum[w - 1] : 0;
    const int excl = base[blockIdx.x] + wbase + inc - v;
    if (i < N_NODES) { off[i] = excl; cursor[i] = excl; }
    if (i == N_NODES) off[i] = excl;     // total edge count
}

// ---------------- combined conv1 GEMM + windowed CSR fill (R18 measured-best).
__global__ __launch_bounds__(256) void conv1_fill(const float* __restrict__ in,
                                                  const float* __restrict__ Wa,
                                                  const float* __restrict__ Wb,
                                                  bf16* __restrict__ out1,
                                                  float* __restrict__ out2,
                                                  const int* __restrict__ src,
                                                  const int* __restrict__ dst,
                                                  int* __restrict__ cursor,
                                                  int* __restrict__ csr, int N) {
    constexpr int K = 128, ROWS = 32, PAD = 36;
    __shared__ float xs[K * PAD];
    const int bid = blockIdx.x;
    if (bid >= MM1_BLOCKS) {
        // windowed fill_csr: pass-major over NWIN windows
        int fb = bid - MM1_BLOCKS;
        int w = fb / DEG_BLOCKS;
        int chunk = fb % DEG_BLOCKS;
        int e = chunk * 256 + threadIdx.x;
        int d = dst[e];
        int lo = w * (N_NODES / NWIN);
        int hi = lo + (N_NODES / NWIN);
        if (d >= lo && d < hi) {
            int p = atomicAdd(&cursor[d], 1);
            csr[p] = src[e];
        }
        return;
    }
    const int row0 = bid * ROWS;
    const int ty = threadIdx.x >> 6;
    const int col = threadIdx.x & 63;
    for (int i = threadIdx.x; i < ROWS * K; i += 256) {
        int r = i / K, c = i % K;
        int row = row0 + r;
        xs[c * PAD + r] = (row < N) ? in[(size_t)row * K + c] : 0.f;
    }
    __syncthreads();
    float a1[8], a2[8];
#pragma unroll
    for (int m = 0; m < 8; ++m) { a1[m] = 0.f; a2[m] = 0.f; }
#pragma unroll 4
    for (int k = 0; k < K; ++k) {
        const float4* xr = (const float4*)(xs + k * PAD + ty * 8);
        float4 xa = xr[0], xb = xr[1];
        float wa = Wa[k * 64 + col];
        float wb = Wb[k * 64 + col];
        a1[0] = fmaf(xa.x, wa, a1[0]); a2[0] = fmaf(xa.x, wb, a2[0]);
        a1[1] = fmaf(xa.y, wa, a1[1]); a2[1] = fmaf(xa.y, wb, a2[1]);
        a1[2] = fmaf(xa.z, wa, a1[2]); a2[2] = fmaf(xa.z, wb, a2[2]);
        a1[3] = fmaf(xa.w, wa, a1[3]); a2[3] = fmaf(xa.w, wb, a2[3]);
        a1[4] = fmaf(xb.x, wa, a1[4]); a2[4] = fmaf(xb.x, wb, a2[4]);
        a1[5] = fmaf(xb.y, wa, a1[5]); a2[5] = fmaf(xb.y, wb, a2[5]);
        a1[6] = fmaf(xb.z, wa, a1[6]); a2[6] = fmaf(xb.z, wb, a2[6]);
        a1[7] = fmaf(xb.w, wa, a1[7]); a2[7] = fmaf(xb.w, wb, a2[7]);
    }
#pragma unroll
    for (int m = 0; m < 8; ++m) {
        int row = row0 + ty * 8 + m;
        if (row < N) {
            unsigned idx = ((unsigned)row << 6) + col;
            out1[idx] = f2bf(a1[m]);
            out2[idx] = a2[m];
        }
    }
}

// ---------------- fused gather + dual GEMM (R13 form: 16-node tile,
// LDS-staged indices): h = ReLU(mean + bias + r) -> LDS(T) -> out = h@W
template <bool OUT1_BF, bool OUT2_BF>
__global__ __launch_bounds__(256) void gather_mm(const bf16* __restrict__ y,
                                                 const float* __restrict__ r,
                                                 const int* __restrict__ csr,
                                                 const int* __restrict__ off,
                                                 const float* __restrict__ bias,
                                                 const float* __restrict__ Wa,
                                                 const float* __restrict__ Wb,
                                                 void* __restrict__ out1v,
                                                 void* __restrict__ out2v, int N) {
    constexpr int K = 64, ROWS = 16, PAD = 20, IDXCAP = 256;
    __shared__ float xs[K * PAD];           // 5 KB
    __shared__ int   idx_s[4][IDXCAP];      // 4 KB (1 KB per wave)
    const int row0 = blockIdx.x * ROWS;     // N % 16 == 0 -> all nodes valid
    const int j  = threadIdx.x & 63;
    const int wv = threadIdx.x >> 6;
    const float bj = bias[j];

    const int nbase = row0 + wv * 4;
    int offs[5];
#pragma unroll
    for (int i = 0; i < 5; ++i) offs[i] = off[nbase + i];
    const int segS = offs[0];
    const int len = offs[4] - segS;
    int* idx_w = idx_s[wv];
    const bool useLds = (len <= IDXCAP);
    if (useLds) {
        for (int i = j; i < len; i += 64)
            idx_w[i] = csr[segS + i];        // coalesced; wave-private slab
    }

    // ---- gather phase: wave wv produces rows wv*4 .. wv*4+3
    for (int m = 0; m < 4; ++m) {
        int lr = wv * 4 + m;
        int node = row0 + lr;
        float acc = 0.f;
        int deg = offs[m + 1] - offs[m];
        if (useLds) {
            int k = offs[m] - segS, s1 = offs[m + 1] - segS;
            for (; k + 15 < s1; k += 16) {
                int sidx[16];
#pragma unroll
                for (int u = 0; u < 16; ++u) sidx[u] = idx_w[k + u];
                float v[16];
#pragma unroll
                for (int u = 0; u < 16; ++u) v[u] = bf2f(y[((unsigned)sidx[u] << 6) + j]);
                float s = 0.f;
#pragma unroll
                for (int u = 0; u < 16; ++u) s += v[u];
                acc += s;
            }
            for (; k + 3 < s1; k += 4) {
                int sa = idx_w[k], sb = idx_w[k + 1], sc = idx_w[k + 2], sd = idx_w[k + 3];
                float va = bf2f(y[((unsigned)sa << 6) + j]);
                float vb = bf2f(y[((unsigned)sb << 6) + j]);
                float vc = bf2f(y[((unsigned)sc << 6) + j]);
                float vd = bf2f(y[((unsigned)sd << 6) + j]);
                acc += (va + vb) + (vc + vd);
            }
            for (; k < s1; ++k)
                acc += bf2f(y[((unsigned)idx_w[k] << 6) + j]);
        } else {
            int k = offs[m], s1 = offs[m + 1];
            for (; k + 15 < s1; k += 16) {
                int sidx[16];
#pragma unroll
                for (int u = 0; u < 16; ++u) sidx[u] = csr[k + u];
                float v[16];
#pragma unroll
                for (int u = 0; u < 16; ++u) v[u] = bf2f(y[((unsigned)sidx[u] << 6) + j]);
                float s = 0.f;
#pragma unroll
                for (int u = 0; u < 16; ++u) s += v[u];
                acc += s;
            }
            for (; k + 3 < s1; k += 4) {
                int sa = csr[k], sb = csr[k + 1], sc = csr[k + 2], sd = csr[k + 3];
                float va = bf2f(y[((unsigned)sa << 6) + j]);
                float vb = bf2f(y[((unsigned)sb << 6) + j]);
                float vc = bf2f(y[((unsigned)sc << 6) + j]);
                float vd = bf2f(y[((unsigned)sd << 6) + j]);
                acc += (va + vb) + (vc + vd);
            }
            for (; k < s1; ++k)
                acc += bf2f(y[((unsigned)csr[k] << 6) + j]);
        }
        float mean = acc / fmaxf((float)deg, 1.f);
        float val = fmaxf(mean + bj + r[((unsigned)node << 6) + j], 0.f);
        xs[j * PAD + lr] = val;     // transposed for GEMM
    }
    __syncthreads();

    // ---- GEMM phase: each wave computes 4 output rows x 64 cols
    float a1[4], a2[4];
#pragma unroll
    for (int m = 0; m < 4; ++m) { a1[m] = 0.f; a2[m] = 0.f; }
#pragma unroll 4
    for (int k = 0; k < K; ++k) {
        const float4 xa = *(const float4*)(xs + k * PAD + wv * 4);  // broadcast
        float wa = Wa[k * 64 + j];
        float wb = Wb[k * 64 + j];
        a1[0] = fmaf(xa.x, wa, a1[0]); a2[0] = fmaf(xa.x, wb, a2[0]);
        a1[1] = fmaf(xa.y, wa, a1[1]); a2[1] = fmaf(xa.y, wb, a2[1]);
        a1[2] = fmaf(xa.z, wa, a1[2]); a2[2] = fmaf(xa.z, wb, a2[2]);
        a1[3] = fmaf(xa.w, wa, a1[3]); a2[3] = fmaf(xa.w, wb, a2[3]);
    }
#pragma unroll
    for (int m = 0; m < 4; ++m) {
        int row = row0 + wv * 4 + m;
        if (row < N) {
            unsigned idx = ((unsigned)row << 6) + j;
            if (OUT1_BF) ((bf16*)out1v)[idx] = f2bf(a1[m]);
            else         ((float*)out1v)[idx] = a1[m];
            if (OUT2_BF) ((bf16*)out2v)[idx] = f2bf(a2[m]);
            else         ((float*)out2v)[idx] = a2[m];
        }
    }
}

// ---------------- fused edge stage, MFMA form (R18, refcheck-validated)
__global__ __launch_bounds__(256) void edge_fused(const bf16* __restrict__ aE,
                                                  const bf16* __restrict__ bE,
                                                  const float* __restrict__ ea,
                                                  const float* __restrict__ Wbot,
                                                  const float* __restrict__ bm1,
                                                  const float* __restrict__ wm2,
                                                  const float* __restrict__ bm2,
                                                  const int* __restrict__ src,
                                                  const int* __restrict__ dst,
                                                  float* __restrict__ out) {
    __shared__ __align__(16) unsigned ea_s[EBLK * 8];  // rows of 16 f16 (2 KB)
    const int t   = threadIdx.x;
    const int eb0 = blockIdx.x * EBLK;
    const int j   = t & 63;
    const int wv  = t >> 6;
    const int lo  = j & 15;     // D col within 16-group / A row
    const int hi  = j >> 4;     // k-block / D row-group

    {   // stage ea -> f16 pairs (coalesced float2 reads)
        const float2* eaf2 = (const float2*)(ea + (size_t)eb0 * 16);
        for (int i = t; i < EBLK * 8; i += 256) {
            float2 f = eaf2[i];
            half2t p;
            p.x = (_Float16)f.x;
            p.y = (_Float16)f.y;
            ea_s[i] = __builtin_bit_cast(unsigned, p);
        }
    }

    // B operand: wb[m][i] = f16(Wbot[k = hi*4+i][col = 16m+lo])
    half4t wb[4];
#pragma unroll
    for (int m = 0; m < 4; ++m)
#pragma unroll
        for (int i = 0; i < 4; ++i)
            wb[m][i] = (_Float16)Wbot[(hi * 4 + i) * 64 + 16 * m + lo];
    float bm1c[4], wm2c[4];
#pragma unroll
    for (int m = 0; m < 4; ++m) {
        bm1c[m] = bm1[16 * m + lo];
        wm2c[m] = wm2[16 * m + lo];
    }
    const float bm2c = bm2[0];

    // wave's 16 edges: lane p holds edge (p&15)'s src/dst
    const int ebw = eb0 + wv * 16;
    const int vsrc = src[ebw + lo];
    const int vdst = dst[ebw + lo];
    __syncthreads();

    // A operand: ea[edge = wv*16 + lo][k = hi*4 .. hi*4+3]  (one ds_read_b64)
    const uint2 a2v = *(const uint2*)(ea_s + (wv * 16 + lo) * 8 + hi * 2);
    const half4t a = __builtin_bit_cast(half4t, a2v);

    f32x4 acc[4];
#pragma unroll
    for (int m = 0; m < 4; ++m)
        acc[m] = (f32x4){bm1c[m], bm1c[m], bm1c[m], bm1c[m]};
#pragma unroll
    for (int m = 0; m < 4; ++m)
        acc[m] = __builtin_amdgcn_mfma_f32_16x16x16f16(a, wb[m], acc[m], 0, 0, 0);

    // per lane: 4 edge rows (hi*4+r), 4 cols (16m+lo)
    const ushort* aU = (const ushort*)aE;
    const ushort* bU = (const ushort*)bE;
    float esum[4];
#pragma unroll
    for (int r = 0; r < 4; ++r) {
        int s = __shfl(vsrc, hi * 4 + r, 16);   // edge (hi*4+r)'s src
        int d = __shfl(vdst, hi * 4 + r, 16);
        const ushort* ap = aU + ((unsigned)s << 6) + lo;
        const ushort* bp = bU + ((unsigned)d << 6) + lo;
        ushort au[4], bu[4];
#pragma unroll
        for (int m = 0; m < 4; ++m) { au[m] = ap[16 * m]; bu[m] = bp[16 * m]; }
        float sum = 0.f;
#pragma unroll
        for (int m = 0; m < 4; ++m) {
            float v = acc[m][r] + bf2f(*(const bf16*)&au[m]) + bf2f(*(const bf16*)&bu[m]);
            sum = fmaf(fmaxf(v, 0.f), wm2c[m], sum);
        }
        esum[r] = sum;
    }
    // reduce over the 16 lanes of each group
#pragma unroll
    for (int o = 1; o < 16; o <<= 1) {
#pragma unroll
        for (int r = 0; r < 4; ++r) esum[r] += __shfl_xor(esum[r], o, 16);
    }
    if (lo == 0) {
#pragma unroll
        for (int r = 0; r < 4; ++r)
            out[ebw + hi * 4 + r] = 1.f / (1.f + __expf(-(esum[r] + bm2c)));
    }
}

extern "C" void kernel_launch(void* const* d_in, const int* in_sizes, int n_in,
                              void* d_out, int out_size, void* d_ws, size_t ws_size,
                              hipStream_t stream) {
    const float* x         = (const float*)d_in[0];
    const float* edge_attr = (const float*)d_in[1];
    const float* W1l       = (const float*)d_in[2];
    const float* b1l       = (const float*)d_in[3];
    const float* W1r       = (const float*)d_in[4];
    const float* W2l       = (const float*)d_in[5];
    const float* b2l       = (const float*)d_in[6];
    const float* W2r       = (const float*)d_in[7];
    const float* Wm1       = (const float*)d_in[8];
    const float* bm1       = (const float*)d_in[9];
    const float* Wm2       = (const float*)d_in[10];
    const float* bm2       = (const float*)d_in[11];
    const int*   ei        = (const int*)d_in[12];   // [2, E] int32
    const int*   src       = ei;
    const int*   dst       = ei + N_EDGES;
    float* out = (float*)d_out;

    int*   degi    = (int*)d_ws;
    int*   off     = degi + 50176;
    int*   cursor  = off + 50432;
    int*   partial = cursor + 50000;
    int*   base    = cursor + 50064;
    int*   csr     = cursor + 50176;
    bf16*  bfA     = (bf16*)(csr + N_EDGES);  // y1 / aE
    bf16*  bfB     = bfA + NODEF;             // y2
    bf16*  bfC     = bfB + NODEF;             // bE
    float* fR      = (float*)(bfC + NODEF);   // r1
    float* fR2     = fR + NODEF;              // r2

    const int N = N_NODES, E = N_EDGES;
    const int gmGrid = (N + 15) / 16;        // 3125
    const int efGrid = E / EBLK;

    // ---- CSR degree + offsets (small, parallel)
    hipMemsetAsync(degi, 0, N_NODES * sizeof(int), stream);
    deg_count_i<<<DEG_BLOCKS, 256, 0, stream>>>(dst, degi, E);
    scan_blocks<<<SCAN_BLOCKS, 1024, 0, stream>>>(degi, partial);
    scan_tops<<<1, 64, 0, stream>>>(partial, base);
    scan_final<<<SCAN_BLOCKS, 1024, 0, stream>>>(degi, base, off, cursor);

    // ---- conv1 GEMM merged with windowed CSR fill (R18 measured-best)
    conv1_fill<<<MM1_BLOCKS + NWIN * DEG_BLOCKS, 256, 0, stream>>>(
        x, W1l, W1r, bfA, fR, src, dst, cursor, csr, N);

    // ---- conv2: gather h1 (from y1,r1) fused with y2 = h1@W2l, r2 = h1@W2r
    gather_mm<true, false><<<gmGrid, 256, 0, stream>>>(
        bfA, fR, csr, off, b1l, W2l, W2r, bfB, fR2, N);

    // ---- edge precompute: gather h2 (from y2,r2) fused with aE/bE = h2@Wm1 halves
    gather_mm<true, true><<<gmGrid, 256, 0, stream>>>(
        bfB, fR2, csr, off, b2l, Wm1, Wm1 + 64 * 64, bfA, bfC, N);

    // ---- fused edge MLP (MFMA)
    edge_fused<<<efGrid, 256, 0, stream>>>(bfA, bfC, edge_attr, Wm1 + 128 * 64,
                                           bm1, Wm2, bm2, src, dst, out);
}

// Round 22
// 317.338 us; speedup vs baseline: 1.1050x; 1.0247x over previous
//
#include <hip/hip_runtime.h>
#include <hip/hip_bf16.h>
#include <math.h>

#define N_NODES 50000
#define N_EDGES 1600000
#define NODE_IN 128
#define HID 64
#define NODEF (N_NODES * HID)   // 3,200,000 elements per node buffer
#define EBLK 64                 // edges per block in edge_fused (E % EBLK == 0)
#define MM1_BLOCKS 1563         // ceil(50000/32)
#define DEG_BLOCKS 6250         // 1.6M / 256
#define NWIN 8                  // dst windows, one per XCD (50000/8 = 6250)
#define SCAN_BLOCKS 49          // ceil(50000/1024)

typedef __hip_bfloat16 bf16;
typedef _Float16 half2t __attribute__((ext_vector_type(2)));
typedef _Float16 half4t __attribute__((ext_vector_type(4)));
typedef float f32x4 __attribute__((ext_vector_type(4)));

__device__ __forceinline__ float bf2f(bf16 v) { return __bfloat162float(v); }
__device__ __forceinline__ bf16 f2bf(float v) { return __float2bfloat16(v); }

// ---------------- degree count (standalone; feeds scan)
__global__ __launch_bounds__(256) void deg_count_i(const int* __restrict__ dst,
                                                   int* __restrict__ degi, int E) {
    int e = blockIdx.x * blockDim.x + threadIdx.x;
    if (e < E) atomicAdd(&degi[dst[e]], 1);
}

// ---------------- hierarchical scan, stage 1: per-block sums
__global__ __launch_bounds__(1024) void scan_blocks(const int* __restrict__ degi,
                                                    int* __restrict__ partial) {
    __shared__ int wsum[16];
    const int t = threadIdx.x;
    const int i = blockIdx.x * 1024 + t;
    const int lane = t & 63, w = t >> 6;
    int v = (i < N_NODES) ? degi[i] : 0;
#pragma unroll
    for (int d = 32; d; d >>= 1) v += __shfl_xor(v, d, 64);
    if (lane == 0) wsum[w] = v;
    __syncthreads();
    if (t == 0) {
        int s = 0;
#pragma unroll
        for (int k = 0; k < 16; ++k) s += wsum[k];
        partial[blockIdx.x] = s;
    }
}

// ---------------- stage 2: exclusive scan of 49 partials (one wave)
__global__ __launch_bounds__(64) void scan_tops(const int* __restrict__ partial,
                                                int* __restrict__ base) {
    const int t = threadIdx.x;
    int v = (t < SCAN_BLOCKS) ? partial[t] : 0;
    int inc = v;
#pragma unroll
    for (int d = 1; d < 64; d <<= 1) {
        int u = __shfl_up(inc, d, 64);
        if (t >= d) inc += u;
    }
    if (t < SCAN_BLOCKS) base[t] = inc - v;
}

// ---------------- stage 3: per-block exclusive scan + base, coalesced writes
__global__ __launch_bounds__(1024) void scan_final(const int* __restrict__ degi,
                                                   const int* __restrict__ base,
                                                   int* __restrict__ off,
                                                   int* __restrict__ cursor) {
    __shared__ int wsum[16];
    const int t = threadIdx.x;
    const int i = blockIdx.x * 1024 + t;
    const int lane = t & 63, w = t >> 6;
    int v = (i < N_NODES) ? degi[i] : 0;
    int inc = v;
#pragma unroll
    for (int d = 1; d < 64; d <<= 1) {
        int u = __shfl_up(inc, d, 64);
        if (lane >= d) inc += u;
    }
    if (lane == 63) wsum[w] = inc;
    __syncthreads();
    if (w == 0) {
        int s = (lane < 16) ? wsum[lane] : 0;
#pragma unroll
        for (int d = 1; d < 16; d <<= 1) {
            int u = __shfl_up(s, d, 64);
            if (lane >= d) s += u;
        }
        if (lane < 16) wsum[lane] = s;   // inclusive wave sums
    }
    __syncthreads();
    const int wbase = (w > 0) ? wsum[w - 1] : 0;
    const int excl = base[blockIdx.x] + wbase + inc - v;
    if (i < N_NODES) { off[i] = excl; cursor[i] = excl; }
    if (i == N_NODES) off[i] = excl;     // total edge count
}

// ---------------- combined conv1 GEMM + XCD-keyed windowed CSR fill.
// Fill block fb handles window (fb & 7): consecutive blockIdx round-robins
// across the 8 XCDs, so ALL stores to window w's 0.8MB csr region issue from
// ONE XCD -> lines fill completely in that XCD's L2 (no cross-XCD partial
// copies) -> ~1x writeback instead of ~16x partial-line amplification.
__global__ __launch_bounds__(256) void conv1_fill(const float* __restrict__ in,
                                                  const float* __restrict__ Wa,
                                                  const float* __restrict__ Wb,
                                                  bf16* __restrict__ out1,
                                                  float* __restrict__ out2,
                                                  const int* __restrict__ src,
                                                  const int* __restrict__ dst,
                                                  int* __restrict__ cursor,
                                                  int* __restrict__ csr, int N) {
    constexpr int K = 128, ROWS = 32, PAD = 36;
    __shared__ float xs[K * PAD];
    const int bid = blockIdx.x;
    if (bid >= MM1_BLOCKS) {
        int fb = bid - MM1_BLOCKS;
        int w = bid & 7;                 // window == this block's XCD key
        int chunk = fb >> 3;             // 0..6249 (each window scans all E)
        int e = chunk * 256 + threadIdx.x;
        int d = dst[e];
        int lo = w * (N_NODES / NWIN);
        int hi = lo + (N_NODES / NWIN);
        if (d >= lo && d < hi) {
            int p = atomicAdd(&cursor[d], 1);
            csr[p] = src[e];
        }
        return;
    }
    const int row0 = bid * ROWS;
    const int ty = threadIdx.x >> 6;
    const int col = threadIdx.x & 63;
    for (int i = threadIdx.x; i < ROWS * K; i += 256) {
        int r = i / K, c = i % K;
        int row = row0 + r;
        xs[c * PAD + r] = (row < N) ? in[(size_t)row * K + c] : 0.f;
    }
    __syncthreads();
    float a1[8], a2[8];
#pragma unroll
    for (int m = 0; m < 8; ++m) { a1[m] = 0.f; a2[m] = 0.f; }
#pragma unroll 4
    for (int k = 0; k < K; ++k) {
        const float4* xr = (const float4*)(xs + k * PAD + ty * 8);
        float4 xa = xr[0], xb = xr[1];
        float wa = Wa[k * 64 + col];
        float wb = Wb[k * 64 + col];
        a1[0] = fmaf(xa.x, wa, a1[0]); a2[0] = fmaf(xa.x, wb, a2[0]);
        a1[1] = fmaf(xa.y, wa, a1[1]); a2[1] = fmaf(xa.y, wb, a2[1]);
        a1[2] = fmaf(xa.z, wa, a1[2]); a2[2] = fmaf(xa.z, wb, a2[2]);
        a1[3] = fmaf(xa.w, wa, a1[3]); a2[3] = fmaf(xa.w, wb, a2[3]);
        a1[4] = fmaf(xb.x, wa, a1[4]); a2[4] = fmaf(xb.x, wb, a2[4]);
        a1[5] = fmaf(xb.y, wa, a1[5]); a2[5] = fmaf(xb.y, wb, a2[5]);
        a1[6] = fmaf(xb.z, wa, a1[6]); a2[6] = fmaf(xb.z, wb, a2[6]);
        a1[7] = fmaf(xb.w, wa, a1[7]); a2[7] = fmaf(xb.w, wb, a2[7]);
    }
#pragma unroll
    for (int m = 0; m < 8; ++m) {
        int row = row0 + ty * 8 + m;
        if (row < N) {
            unsigned idx = ((unsigned)row << 6) + col;
            out1[idx] = f2bf(a1[m]);
            out2[idx] = a2[m];
        }
    }
}

// ---------------- fused gather + dual GEMM (R13 form: 16-node tile,
// LDS-staged indices): h = ReLU(mean + bias + r) -> LDS(T) -> out = h@W
template <bool OUT1_BF, bool OUT2_BF>
__global__ __launch_bounds__(256) void gather_mm(const bf16* __restrict__ y,
                                                 const float* __restrict__ r,
                                                 const int* __restrict__ csr,
                                                 const int* __restrict__ off,
                                                 const float* __restrict__ bias,
                                                 const float* __restrict__ Wa,
                                                 const float* __restrict__ Wb,
                                                 void* __restrict__ out1v,
                                                 void* __restrict__ out2v, int N) {
    constexpr int K = 64, ROWS = 16, PAD = 20, IDXCAP = 256;
    __shared__ float xs[K * PAD];           // 5 KB
    __shared__ int   idx_s[4][IDXCAP];      // 4 KB (1 KB per wave)
    const int row0 = blockIdx.x * ROWS;     // N % 16 == 0 -> all nodes valid
    const int j  = threadIdx.x & 63;
    const int wv = threadIdx.x >> 6;
    const float bj = bias[j];

    const int nbase = row0 + wv * 4;
    int offs[5];
#pragma unroll
    for (int i = 0; i < 5; ++i) offs[i] = off[nbase + i];
    const int segS = offs[0];
    const int len = offs[4] - segS;
    int* idx_w = idx_s[wv];
    const bool useLds = (len <= IDXCAP);
    if (useLds) {
        for (int i = j; i < len; i += 64)
            idx_w[i] = csr[segS + i];        // coalesced; wave-private slab
    }

    // ---- gather phase: wave wv produces rows wv*4 .. wv*4+3
    for (int m = 0; m < 4; ++m) {
        int lr = wv * 4 + m;
        int node = row0 + lr;
        float acc = 0.f;
        int deg = offs[m + 1] - offs[m];
        if (useLds) {
            int k = offs[m] - segS, s1 = offs[m + 1] - segS;
            for (; k + 15 < s1; k += 16) {
                int sidx[16];
#pragma unroll
                for (int u = 0; u < 16; ++u) sidx[u] = idx_w[k + u];
                float v[16];
#pragma unroll
                for (int u = 0; u < 16; ++u) v[u] = bf2f(y[((unsigned)sidx[u] << 6) + j]);
                float s = 0.f;
#pragma unroll
                for (int u = 0; u < 16; ++u) s += v[u];
                acc += s;
            }
            for (; k + 3 < s1; k += 4) {
                int sa = idx_w[k], sb = idx_w[k + 1], sc = idx_w[k + 2], sd = idx_w[k + 3];
                float va = bf2f(y[((unsigned)sa << 6) + j]);
                float vb = bf2f(y[((unsigned)sb << 6) + j]);
                float vc = bf2f(y[((unsigned)sc << 6) + j]);
                float vd = bf2f(y[((unsigned)sd << 6) + j]);
                acc += (va + vb) + (vc + vd);
            }
            for (; k < s1; ++k)
                acc += bf2f(y[((unsigned)idx_w[k] << 6) + j]);
        } else {
            int k = offs[m], s1 = offs[m + 1];
            for (; k + 15 < s1; k += 16) {
                int sidx[16];
#pragma unroll
                for (int u = 0; u < 16; ++u) sidx[u] = csr[k + u];
                float v[16];
#pragma unroll
                for (int u = 0; u < 16; ++u) v[u] = bf2f(y[((unsigned)sidx[u] << 6) + j]);
                float s = 0.f;
#pragma unroll
                for (int u = 0; u < 16; ++u) s += v[u];
                acc += s;
            }
            for (; k + 3 < s1; k += 4) {
                int sa = csr[k], sb = csr[k + 1], sc = csr[k + 2], sd = csr[k + 3];
                float va = bf2f(y[((unsigned)sa << 6) + j]);
                float vb = bf2f(y[((unsigned)sb << 6) + j]);
                float vc = bf2f(y[((unsigned)sc << 6) + j]);
                float vd = bf2f(y[((unsigned)sd << 6) + j]);
                acc += (va + vb) + (vc + vd);
            }
            for (; k < s1; ++k)
                acc += bf2f(y[((unsigned)csr[k] << 6) + j]);
        }
        float mean = acc / fmaxf((float)deg, 1.f);
        float val = fmaxf(mean + bj + r[((unsigned)node << 6) + j], 0.f);
        xs[j * PAD + lr] = val;     // transposed for GEMM
    }
    __syncthreads();

    // ---- GEMM phase: each wave computes 4 output rows x 64 cols
    float a1[4], a2[4];
#pragma unroll
    for (int m = 0; m < 4; ++m) { a1[m] = 0.f; a2[m] = 0.f; }
#pragma unroll 4
    for (int k = 0; k < K; ++k) {
        const float4 xa = *(const float4*)(xs + k * PAD + wv * 4);  // broadcast
        float wa = Wa[k * 64 + j];
        float wb = Wb[k * 64 + j];
        a1[0] = fmaf(xa.x, wa, a1[0]); a2[0] = fmaf(xa.x, wb, a2[0]);
        a1[1] = fmaf(xa.y, wa, a1[1]); a2[1] = fmaf(xa.y, wb, a2[1]);
        a1[2] = fmaf(xa.z, wa, a1[2]); a2[2] = fmaf(xa.z, wb, a2[2]);
        a1[3] = fmaf(xa.w, wa, a1[3]); a2[3] = fmaf(xa.w, wb, a2[3]);
    }
#pragma unroll
    for (int m = 0; m < 4; ++m) {
        int row = row0 + wv * 4 + m;
        if (row < N) {
            unsigned idx = ((unsigned)row << 6) + j;
            if (OUT1_BF) ((bf16*)out1v)[idx] = f2bf(a1[m]);
            else         ((float*)out1v)[idx] = a1[m];
            if (OUT2_BF) ((bf16*)out2v)[idx] = f2bf(a2[m]);
            else         ((float*)out2v)[idx] = a2[m];
        }
    }
}

// ---------------- fused edge stage, MFMA form (R18, refcheck-validated)
__global__ __launch_bounds__(256) void edge_fused(const bf16* __restrict__ aE,
                                                  const bf16* __restrict__ bE,
                                                  const float* __restrict__ ea,
                                                  const float* __restrict__ Wbot,
                                                  const float* __restrict__ bm1,
                                                  const float* __restrict__ wm2,
                                                  const float* __restrict__ bm2,
                                                  const int* __restrict__ src,
                                                  const int* __restrict__ dst,
                                                  float* __restrict__ out) {
    __shared__ __align__(16) unsigned ea_s[EBLK * 8];  // rows of 16 f16 (2 KB)
    const int t   = threadIdx.x;
    const int eb0 = blockIdx.x * EBLK;
    const int j   = t & 63;
    const int wv  = t >> 6;
    const int lo  = j & 15;     // D col within 16-group / A row
    const int hi  = j >> 4;     // k-block / D row-group

    {   // stage ea -> f16 pairs (coalesced float2 reads)
        const float2* eaf2 = (const float2*)(ea + (size_t)eb0 * 16);
        for (int i = t; i < EBLK * 8; i += 256) {
            float2 f = eaf2[i];
            half2t p;
            p.x = (_Float16)f.x;
            p.y = (_Float16)f.y;
            ea_s[i] = __builtin_bit_cast(unsigned, p);
        }
    }

    // B operand: wb[m][i] = f16(Wbot[k = hi*4+i][col = 16m+lo])
    half4t wb[4];
#pragma unroll
    for (int m = 0; m < 4; ++m)
#pragma unroll
        for (int i = 0; i < 4; ++i)
            wb[m][i] = (_Float16)Wbot[(hi * 4 + i) * 64 + 16 * m + lo];
    float bm1c[4], wm2c[4];
#pragma unroll
    for (int m = 0; m < 4; ++m) {
        bm1c[m] = bm1[16 * m + lo];
        wm2c[m] = wm2[16 * m + lo];
    }
    const float bm2c = bm2[0];

    // wave's 16 edges: lane p holds edge (p&15)'s src/dst
    const int ebw = eb0 + wv * 16;
    const int vsrc = src[ebw + lo];
    const int vdst = dst[ebw + lo];
    __syncthreads();

    // A operand: ea[edge = wv*16 + lo][k = hi*4 .. hi*4+3]  (one ds_read_b64)
    const uint2 a2v = *(const uint2*)(ea_s + (wv * 16 + lo) * 8 + hi * 2);
    const half4t a = __builtin_bit_cast(half4t, a2v);

    f32x4 acc[4];
#pragma unroll
    for (int m = 0; m < 4; ++m)
        acc[m] = (f32x4){bm1c[m], bm1c[m], bm1c[m], bm1c[m]};
#pragma unroll
    for (int m = 0; m < 4; ++m)
        acc[m] = __builtin_amdgcn_mfma_f32_16x16x16f16(a, wb[m], acc[m], 0, 0, 0);

    // per lane: 4 edge rows (hi*4+r), 4 cols (16m+lo)
    const ushort* aU = (const ushort*)aE;
    const ushort* bU = (const ushort*)bE;
    float esum[4];
#pragma unroll
    for (int r = 0; r < 4; ++r) {
        int s = __shfl(vsrc, hi * 4 + r, 16);   // edge (hi*4+r)'s src
        int d = __shfl(vdst, hi * 4 + r, 16);
        const ushort* ap = aU + ((unsigned)s << 6) + lo;
        const ushort* bp = bU + ((unsigned)d << 6) + lo;
        ushort au[4], bu[4];
#pragma unroll
        for (int m = 0; m < 4; ++m) { au[m] = ap[16 * m]; bu[m] = bp[16 * m]; }
        float sum = 0.f;
#pragma unroll
        for (int m = 0; m < 4; ++m) {
            float v = acc[m][r] + bf2f(*(const bf16*)&au[m]) + bf2f(*(const bf16*)&bu[m]);
            sum = fmaf(fmaxf(v, 0.f), wm2c[m], sum);
        }
        esum[r] = sum;
    }
    // reduce over the 16 lanes of each group
#pragma unroll
    for (int o = 1; o < 16; o <<= 1) {
#pragma unroll
        for (int r = 0; r < 4; ++r) esum[r] += __shfl_xor(esum[r], o, 16);
    }
    if (lo == 0) {
#pragma unroll
        for (int r = 0; r < 4; ++r)
            out[ebw + hi * 4 + r] = 1.f / (1.f + __expf(-(esum[r] + bm2c)));
    }
}

extern "C" void kernel_launch(void* const* d_in, const int* in_sizes, int n_in,
                              void* d_out, int out_size, void* d_ws, size_t ws_size,
                              hipStream_t stream) {
    const float* x         = (const float*)d_in[0];
    const float* edge_attr = (const float*)d_in[1];
    const float* W1l       = (const float*)d_in[2];
    const float* b1l       = (const float*)d_in[3];
    const float* W1r       = (const float*)d_in[4];
    const float* W2l       = (const float*)d_in[5];
    const float* b2l       = (const float*)d_in[6];
    const float* W2r       = (const float*)d_in[7];
    const float* Wm1       = (const float*)d_in[8];
    const float* bm1       = (const float*)d_in[9];
    const float* Wm2       = (const float*)d_in[10];
    const float* bm2       = (const float*)d_in[11];
    const int*   ei        = (const int*)d_in[12];   // [2, E] int32
    const int*   src       = ei;
    const int*   dst       = ei + N_EDGES;
    float* out = (float*)d_out;

    int*   degi    = (int*)d_ws;
    int*   off     = degi + 50176;
    int*   cursor  = off + 50432;
    int*   partial = cursor + 50000;
    int*   base    = cursor + 50064;
    int*   csr     = cursor + 50176;
    bf16*  bfA     = (bf16*)(csr + N_EDGES);  // y1 / aE
    bf16*  bfB     = bfA + NODEF;             // y2
    bf16*  bfC     = bfB + NODEF;             // bE
    float* fR      = (float*)(bfC + NODEF);   // r1
    float* fR2     = fR + NODEF;              // r2

    const int N = N_NODES, E = N_EDGES;
    const int gmGrid = (N + 15) / 16;        // 3125
    const int efGrid = E / EBLK;

    // ---- CSR degree + offsets (small, parallel)
    hipMemsetAsync(degi, 0, N_NODES * sizeof(int), stream);
    deg_count_i<<<DEG_BLOCKS, 256, 0, stream>>>(dst, degi, E);
    scan_blocks<<<SCAN_BLOCKS, 1024, 0, stream>>>(degi, partial);
    scan_tops<<<1, 64, 0, stream>>>(partial, base);
    scan_final<<<SCAN_BLOCKS, 1024, 0, stream>>>(degi, base, off, cursor);

    // ---- conv1 GEMM merged with XCD-keyed windowed CSR fill
    conv1_fill<<<MM1_BLOCKS + NWIN * DEG_BLOCKS, 256, 0, stream>>>(
        x, W1l, W1r, bfA, fR, src, dst, cursor, csr, N);

    // ---- conv2: gather h1 (from y1,r1) fused with y2 = h1@W2l, r2 = h1@W2r
    gather_mm<true, false><<<gmGrid, 256, 0, stream>>>(
        bfA, fR, csr, off, b1l, W2l, W2r, bfB, fR2, N);

    // ---- edge precompute: gather h2 (from y2,r2) fused with aE/bE = h2@Wm1 halves
    gather_mm<true, true><<<gmGrid, 256, 0, stream>>>(
        bfB, fR2, csr, off, b2l, Wm1, Wm1 + 64 * 64, bfA, bfC, N);

    // ---- fused edge MLP (MFMA)
    edge_fused<<<efGrid, 256, 0, stream>>>(bfA, bfC, edge_attr, Wm1 + 128 * 64,
                                           bm1, Wm2, bm2, src, dst, out);
}